// Round 7
// baseline (209.278 us; speedup 1.0000x reference)
//
#include <hip/hip_runtime.h>
#include <math.h>

typedef float f2 __attribute__((ext_vector_type(2)));
typedef float f2u __attribute__((ext_vector_type(2), aligned(4)));
typedef float f4 __attribute__((ext_vector_type(4)));

#define BN 8
#define CIN 3
#define HH 512
#define WW 512
#define KK 9
#define PATCH 27
#define TAPBLK 100  // per-tap: 28 (wy,wx) pairs | wm[28] | 3x f4 contraction | f4 bias

// ws layout, tap k block of 100 floats:
//  r in [0,56):  pair q=r>>1, half=r&1 -> w_off[(2k+half)*27+q], q>=27 -> 0
//  r in [56,84): i=r-56 -> w_off[(18+k)*27+i], i>=27 -> 0
//  r in [84,96): j=r-84, c=j>>2, o=j&3 -> o<3 ? w_def[o*27 + c*9 + k] : 0
//  r in [96,100): (b_off[2k], b_off[2k+1], b_off[18+k], 0)
__global__ void reorder_weights(const float* __restrict__ w_off,
                                const float* __restrict__ b_off,
                                const float* __restrict__ w_def,
                                float* __restrict__ ws)
{
    for (int idx = threadIdx.x; idx < KK * TAPBLK; idx += blockDim.x) {
        const int k = idx / TAPBLK;
        const int r = idx % TAPBLK;
        float v = 0.0f;
        if (r < 56) {
            const int q = r >> 1, half = r & 1;
            if (q < PATCH) v = w_off[(2 * k + half) * PATCH + q];
        } else if (r < 84) {
            const int i = r - 56;
            if (i < PATCH) v = w_off[(18 + k) * PATCH + i];
        } else if (r < 96) {
            const int j = r - 84;
            const int c = j >> 2, o = j & 3;
            if (o < 3) v = w_def[o * PATCH + c * KK + k];
        } else {
            const int e = r - 96;
            if (e == 0)      v = b_off[2 * k];
            else if (e == 1) v = b_off[2 * k + 1];
            else if (e == 2) v = b_off[18 + k];
        }
        ws[idx] = v;
    }
}

// patch elem i = c*9 + t for pixel A (row h0) and B (row h0+1); rows flat [c][d][e] = c*12+d*3+e
#define PA(i) ((i) < PATCH ? rows[((i) / 9) * 12 + (((i) % 9) / 3) * 3 + ((i) % 3)] : 0.0f)
#define PB(i) ((i) < PATCH ? rows[((i) / 9) * 12 + (((i) % 9) / 3 + 1) * 3 + ((i) % 3)] : 0.0f)

__device__ __forceinline__ void tap_px(
    const float* __restrict__ xb, const size_t plane,
    const int hpx, const int w, const int k,
    const f2 oyx, const float om,
    const f4* wd,               // LDS: 3 f4 = (wd0,wd1,wd2,0) per input channel c
    f2& acc01, float& acc2)
{
    const float m = 1.0f / (1.0f + __expf(-om));

    const float py = (float)hpx + (float)(k / 3 - 1) + oyx.x;
    const float px = (float)w   + (float)(k % 3 - 1) + oyx.y;
    const float y0f = floorf(py);
    const float x0f = floorf(px);
    const float dy = py - y0f;
    const float dx = px - x0f;
    const int y0 = (int)y0f;
    const int x0 = (int)x0f;

    const f2 dxp = { 1.0f - dx, dx };
    const f2 wT = dxp * (1.0f - dy);   // (w00, w01)
    const f2 wB = dxp * dy;            // (w10, w11)

    const int interior = (y0 >= 0) & (y0 + 1 < HH) & (x0 >= 0) & (x0 + 1 < WW);

    if (__all(interior)) {
        const int idx = y0 * WW + x0;
        #pragma unroll
        for (int c = 0; c < CIN; ++c) {
            const float* xp = xb + c * plane + idx;
            const f2 vT = *(const f2u*)(xp);
            const f2 vB = *(const f2u*)(xp + WW);
            f2 s = vT * wT;
            s = __builtin_elementwise_fma(vB, wB, s);
            const float val = (s.x + s.y) * m;
            const f4 wq = wd[c];
            const f2 w01 = { wq.x, wq.y };
            const f2 vv = { val, val };
            acc01 = __builtin_elementwise_fma(w01, vv, acc01);
            acc2 = fmaf(wq.z, val, acc2);
        }
    } else {
        const bool vy0 = (y0 >= 0)     & (y0 < HH);
        const bool vy1 = (y0 + 1 >= 0) & (y0 + 1 < HH);
        const bool vx0 = (x0 >= 0)     & (x0 < WW);
        const bool vx1 = (x0 + 1 >= 0) & (x0 + 1 < WW);

        const int yc0 = min(max(y0, 0), HH - 1);
        const int yc1 = min(max(y0 + 1, 0), HH - 1);
        const int xc0 = min(max(x0, 0), WW - 1);
        const int xc1 = min(max(x0 + 1, 0), WW - 1);

        #pragma unroll
        for (int c = 0; c < CIN; ++c) {
            const float* xp = xb + c * plane;
            const float v00 = (vy0 & vx0) ? xp[yc0 * WW + xc0] : 0.0f;
            const float v01 = (vy0 & vx1) ? xp[yc0 * WW + xc1] : 0.0f;
            const float v10 = (vy1 & vx0) ? xp[yc1 * WW + xc0] : 0.0f;
            const float v11 = (vy1 & vx1) ? xp[yc1 * WW + xc1] : 0.0f;

            const float val =
                (v00 * wT.x + v01 * wT.y + v10 * wB.x + v11 * wB.y) * m;
            const f4 wq = wd[c];
            const f2 w01 = { wq.x, wq.y };
            const f2 vv = { val, val };
            acc01 = __builtin_elementwise_fma(w01, vv, acc01);
            acc2 = fmaf(wq.z, val, acc2);
        }
    }
}

__global__ __launch_bounds__(256) void deform_fused_kernel(
    const float* __restrict__ x,
    const float* __restrict__ wsw,    // reordered weights, 900 floats
    const float* __restrict__ b_def,
    float* __restrict__ out)
{
    __shared__ __attribute__((aligned(16))) float s_w[KK * TAPBLK];  // 900 floats
    __shared__ float s_bdef[3];

    {
        const int tid = threadIdx.x;
        const f4* src4 = (const f4*)wsw;
        f4* dst4 = (f4*)s_w;
        if (tid < KK * TAPBLK / 4) dst4[tid] = src4[tid];   // 225 f4
        if (tid < 3) s_bdef[tid] = b_def[tid];
    }
    __syncthreads();

    const int w = blockIdx.x * blockDim.x + threadIdx.x;
    const int h0 = 2 * blockIdx.y;          // pixel A row; pixel B = h0+1
    const int b = blockIdx.z;

    const size_t plane = (size_t)HH * WW;
    const float* xb = x + (size_t)b * CIN * plane;

    // ---- shared patch rows h0-1 .. h0+2, cols w-1..w+1, all channels ----
    float rows[CIN * 12];   // [c][d][e], d=0..3, e=0..2
    #pragma unroll
    for (int c = 0; c < CIN; ++c) {
        const float* xp = xb + c * plane;
        #pragma unroll
        for (int d = 0; d < 4; ++d) {
            const int yy = h0 - 1 + d;
            #pragma unroll
            for (int e = 0; e < 3; ++e) {
                const int xx = w - 1 + e;
                const bool in = (yy >= 0) & (yy < HH) & (xx >= 0) & (xx < WW);
                rows[c * 12 + d * 3 + e] = in ? xp[yy * WW + xx] : 0.0f;
            }
        }
    }

    f2 accA01 = { s_bdef[0], s_bdef[1] };
    float accA2 = s_bdef[2];
    f2 accB01 = accA01;
    float accB2 = accA2;

    #pragma unroll 1
    for (int k = 0; k < KK; ++k) {
        const float* blk = &s_w[k * TAPBLK];
        const f4* pw = (const f4*)blk;          // 14 f4 = 28 (wy,wx) pairs
        const f4* pm = (const f4*)(blk + 56);   // 7 f4 = wm[28]
        const f4* wd = (const f4*)(blk + 84);   // 3 f4 contraction
        const f4 bias = *(const f4*)(blk + 96); // (boy, box, bom, 0)

        f2 oyxA = { bias.x, bias.y };
        f2 oyxB = oyxA;
        float omA = bias.z, omB = bias.z;

        #pragma unroll
        for (int j = 0; j < 14; ++j) {
            const f4 wq = pw[j];
            const f2 w0 = { wq.x, wq.y };
            const f2 w1 = { wq.z, wq.w };
            {
                const float a0 = PA(2 * j), a1 = PA(2 * j + 1);
                const f2 p0 = { a0, a0 }, p1 = { a1, a1 };
                oyxA = __builtin_elementwise_fma(w0, p0, oyxA);
                oyxA = __builtin_elementwise_fma(w1, p1, oyxA);
            }
            {
                const float b0 = PB(2 * j), b1 = PB(2 * j + 1);
                const f2 p0 = { b0, b0 }, p1 = { b1, b1 };
                oyxB = __builtin_elementwise_fma(w0, p0, oyxB);
                oyxB = __builtin_elementwise_fma(w1, p1, oyxB);
            }
        }
        #pragma unroll
        for (int j = 0; j < 7; ++j) {
            const f4 wm4 = pm[j];
            omA = fmaf(wm4.x, PA(4 * j),     omA);
            omA = fmaf(wm4.y, PA(4 * j + 1), omA);
            omA = fmaf(wm4.z, PA(4 * j + 2), omA);
            omA = fmaf(wm4.w, PA(4 * j + 3), omA);
            omB = fmaf(wm4.x, PB(4 * j),     omB);
            omB = fmaf(wm4.y, PB(4 * j + 1), omB);
            omB = fmaf(wm4.z, PB(4 * j + 2), omB);
            omB = fmaf(wm4.w, PB(4 * j + 3), omB);
        }

        tap_px(xb, plane, h0,     w, k, oyxA, omA, wd, accA01, accA2);
        tap_px(xb, plane, h0 + 1, w, k, oyxB, omB, wd, accB01, accB2);
    }

    const size_t base = (size_t)b * (CIN * plane) + (size_t)h0 * WW + w;
    out[base]                  = accA01.x;
    out[base + plane]          = accA01.y;
    out[base + 2 * plane]      = accA2;
    out[base + WW]             = accB01.x;
    out[base + WW + plane]     = accB01.y;
    out[base + WW + 2 * plane] = accB2;
}

extern "C" void kernel_launch(void* const* d_in, const int* in_sizes, int n_in,
                              void* d_out, int out_size, void* d_ws, size_t ws_size,
                              hipStream_t stream) {
    const float* x     = (const float*)d_in[0];
    const float* w_off = (const float*)d_in[1];
    const float* b_off = (const float*)d_in[2];
    const float* w_def = (const float*)d_in[3];
    const float* b_def = (const float*)d_in[4];
    float* out = (float*)d_out;
    float* wsw = (float*)d_ws;   // 900 floats of reordered weights

    reorder_weights<<<1, 256, 0, stream>>>(w_off, b_off, w_def, wsw);

    dim3 block(256, 1, 1);
    dim3 grid(WW / 256, HH / 2, BN);  // (2, 256, 8)
    deform_fused_kernel<<<grid, block, 0, stream>>>(x, wsw, b_def, out);
}

// Round 8
// 183.262 us; speedup vs baseline: 1.1420x; 1.1420x over previous
//
#include <hip/hip_runtime.h>
#include <math.h>

typedef float f2 __attribute__((ext_vector_type(2)));
typedef float f2u __attribute__((ext_vector_type(2), aligned(4)));
typedef float f4 __attribute__((ext_vector_type(4)));

#define BN 8
#define CIN 3
#define HH 512
#define WW 512
#define KK 9
#define PATCH 27
#define TAPBLK 96  // 56 (wy,wx) pair floats | 28 wm | 12 contraction = 96 = 6x dwordx16

// ws layout, tap k block of 96 floats (base 64B-aligned):
//  r in [0,56):  pair q=r>>1, half=r&1 -> w_off[(2k+half)*27+q], q>=27 -> 0
//  r in [56,84): i=r-56 -> w_off[(18+k)*27+i], i>=27 -> 0
//  r in [84,96): j=r-84, c=j>>2, o=j&3 -> o<3 ? w_def[o*27 + c*9 + k] : 0
__global__ void reorder_weights(const float* __restrict__ w_off,
                                const float* __restrict__ w_def,
                                float* __restrict__ ws)
{
    for (int idx = threadIdx.x; idx < KK * TAPBLK; idx += blockDim.x) {
        const int k = idx / TAPBLK;
        const int r = idx % TAPBLK;
        float v = 0.0f;
        if (r < 56) {
            const int q = r >> 1, half = r & 1;
            if (q < PATCH) v = w_off[(2 * k + half) * PATCH + q];
        } else if (r < 84) {
            const int i = r - 56;
            if (i < PATCH) v = w_off[(18 + k) * PATCH + i];
        } else {
            const int j = r - 84;
            const int c = j >> 2, o = j & 3;
            if (o < 3) v = w_def[o * PATCH + c * KK + k];
        }
        ws[idx] = v;
    }
}

__global__ __launch_bounds__(256) void deform_fused_kernel(
    const float* __restrict__ x,
    const float* __restrict__ wsw,    // reordered weights, 864 floats (uniform -> SMEM)
    const float* __restrict__ b_off,
    const float* __restrict__ b_def,
    float* __restrict__ out)
{
    const int w = blockIdx.x * blockDim.x + threadIdx.x;
    const int h = blockIdx.y;
    const int b = blockIdx.z;

    const size_t plane = (size_t)HH * WW;
    const float* xb = x + (size_t)b * CIN * plane;

    // ---- 3x3x3 zero-padded patch, flat index = c*9 + t; pad elem 27 = 0 ----
    float patch[28];
    patch[27] = 0.0f;
    #pragma unroll
    for (int c = 0; c < CIN; ++c) {
        const float* xp = xb + c * plane;
        #pragma unroll
        for (int t = 0; t < KK; ++t) {
            const int yy = h + t / 3 - 1;
            const int xx = w + t % 3 - 1;
            const bool in = (yy >= 0) & (yy < HH) & (xx >= 0) & (xx < WW);
            patch[c * KK + t] = in ? xp[yy * WW + xx] : 0.0f;
        }
    }

    f2 acc01 = { b_def[0], b_def[1] };
    float acc2 = b_def[2];

    #pragma unroll 1
    for (int k = 0; k < KK; ++k) {
        const float* blk = wsw + k * TAPBLK;   // uniform address -> s_load

        // ---- per-tap conv: (oy,ox) packed, om scalar; weights from SGPRs ----
        f2 oyx = { b_off[2 * k], b_off[2 * k + 1] };
        float om = b_off[18 + k];

        #pragma unroll
        for (int j = 0; j < 14; ++j) {
            const f4 wq = *(const f4*)(blk + 4 * j);
            const float p0 = patch[2 * j];
            const float p1 = patch[2 * j + 1];
            const f2 w0 = { wq.x, wq.y };
            const f2 w1 = { wq.z, wq.w };
            const f2 pp0 = { p0, p0 };
            const f2 pp1 = { p1, p1 };
            oyx = __builtin_elementwise_fma(w0, pp0, oyx);
            oyx = __builtin_elementwise_fma(w1, pp1, oyx);
        }
        #pragma unroll
        for (int j = 0; j < 7; ++j) {
            const f4 wm4 = *(const f4*)(blk + 56 + 4 * j);
            om = fmaf(wm4.x, patch[4 * j],     om);
            om = fmaf(wm4.y, patch[4 * j + 1], om);
            om = fmaf(wm4.z, patch[4 * j + 2], om);
            om = fmaf(wm4.w, patch[4 * j + 3], om);
        }

        const float m = 1.0f / (1.0f + __expf(-om));

        const float py = (float)h + (float)(k / 3 - 1) + oyx.x;
        const float px = (float)w + (float)(k % 3 - 1) + oyx.y;
        const float y0f = floorf(py);
        const float x0f = floorf(px);
        const float dy = py - y0f;
        const float dx = px - x0f;
        const int y0 = (int)y0f;
        const int x0 = (int)x0f;

        const f2 dxp = { 1.0f - dx, dx };
        const f2 wT = dxp * (1.0f - dy);   // (w00, w01)
        const f2 wB = dxp * dy;            // (w10, w11)

        const int interior = (y0 >= 0) & (y0 + 1 < HH) & (x0 >= 0) & (x0 + 1 < WW);

        if (__all(interior)) {
            const int idx = y0 * WW + x0;
            #pragma unroll
            for (int c = 0; c < CIN; ++c) {
                const float* xp = xb + c * plane + idx;
                const f2 vT = *(const f2u*)(xp);
                const f2 vB = *(const f2u*)(xp + WW);
                f2 s = vT * wT;
                s = __builtin_elementwise_fma(vB, wB, s);
                const float val = (s.x + s.y) * m;
                const f4 wq = *(const f4*)(blk + 84 + 4 * c);
                const f2 w01 = { wq.x, wq.y };
                const f2 vv = { val, val };
                acc01 = __builtin_elementwise_fma(w01, vv, acc01);
                acc2 = fmaf(wq.z, val, acc2);
            }
        } else {
            const bool vy0 = (y0 >= 0)     & (y0 < HH);
            const bool vy1 = (y0 + 1 >= 0) & (y0 + 1 < HH);
            const bool vx0 = (x0 >= 0)     & (x0 < WW);
            const bool vx1 = (x0 + 1 >= 0) & (x0 + 1 < WW);

            const int yc0 = min(max(y0, 0), HH - 1);
            const int yc1 = min(max(y0 + 1, 0), HH - 1);
            const int xc0 = min(max(x0, 0), WW - 1);
            const int xc1 = min(max(x0 + 1, 0), WW - 1);

            #pragma unroll
            for (int c = 0; c < CIN; ++c) {
                const float* xp = xb + c * plane;
                const float v00 = (vy0 & vx0) ? xp[yc0 * WW + xc0] : 0.0f;
                const float v01 = (vy0 & vx1) ? xp[yc0 * WW + xc1] : 0.0f;
                const float v10 = (vy1 & vx0) ? xp[yc1 * WW + xc0] : 0.0f;
                const float v11 = (vy1 & vx1) ? xp[yc1 * WW + xc1] : 0.0f;

                const float val =
                    (v00 * wT.x + v01 * wT.y + v10 * wB.x + v11 * wB.y) * m;
                const f4 wq = *(const f4*)(blk + 84 + 4 * c);
                const f2 w01 = { wq.x, wq.y };
                const f2 vv = { val, val };
                acc01 = __builtin_elementwise_fma(w01, vv, acc01);
                acc2 = fmaf(wq.z, val, acc2);
            }
        }
    }

    const size_t base = (size_t)b * (CIN * plane) + (size_t)h * WW + w;
    out[base]             = acc01.x;
    out[base + plane]     = acc01.y;
    out[base + 2 * plane] = acc2;
}

extern "C" void kernel_launch(void* const* d_in, const int* in_sizes, int n_in,
                              void* d_out, int out_size, void* d_ws, size_t ws_size,
                              hipStream_t stream) {
    const float* x     = (const float*)d_in[0];
    const float* w_off = (const float*)d_in[1];
    const float* b_off = (const float*)d_in[2];
    const float* w_def = (const float*)d_in[3];
    const float* b_def = (const float*)d_in[4];
    float* out = (float*)d_out;
    float* wsw = (float*)d_ws;   // 864 floats of reordered weights

    reorder_weights<<<1, 256, 0, stream>>>(w_off, w_def, wsw);

    dim3 block(256, 1, 1);
    dim3 grid(WW / 256, HH, BN);  // (2, 512, 8)
    deform_fused_kernel<<<grid, block, 0, stream>>>(x, wsw, b_off, b_def, out);
}